// Round 1
// baseline (50.707 us; speedup 1.0000x reference)
//
#include <hip/hip_runtime.h>
#include <math.h>

constexpr int NUM_HEADS    = 32;
constexpr int NUM_KV_HEADS = 8;
constexpr int HEAD_DIM     = 128;
constexpr int BS           = 16;
constexpr int KV_LEN       = 2048;
constexpr int GROUP        = NUM_HEADS / NUM_KV_HEADS; // 4
constexpr int NCHUNK       = 8;
constexpr int CHUNK        = KV_LEN / NCHUNK;          // 256

// Partial flash-decode: one block per (b, kv_head, chunk).
// 256 threads = 4 waves; each wave processes 4 KV positions per iter
// (16 lanes per position, each lane owns dims [sub*4,sub*4+4) U [64+sub*4, ...+4)).
__global__ __launch_bounds__(256, 4) void attn_partial_kernel(
    const float* __restrict__ q,
    const float* __restrict__ knew,
    const float* __restrict__ vnew,
    const float* __restrict__ k_cache,
    const float* __restrict__ v_cache,
    const int*   __restrict__ page_indices,
    float* __restrict__ ws_o,
    float* __restrict__ ws_m,
    float* __restrict__ ws_s)
{
    const int bid   = blockIdx.x;
    const int chunk = bid % NCHUNK;
    const int h     = (bid / NCHUNK) % NUM_KV_HEADS;
    const int b     = bid / (NCHUNK * NUM_KV_HEADS);

    const int tid  = threadIdx.x;
    const int wid  = tid >> 6;
    const int lane = tid & 63;
    const int g    = lane >> 4;   // position slot within wave
    const int sub  = lane & 15;   // dim slice

    // fold SCALE and log2(e) into q so softmax uses exp2f directly
    const float qscale = 0.08838834764831845f * 1.4426950408889634f;

    float qv[GROUP][8];
#pragma unroll
    for (int hg = 0; hg < GROUP; ++hg) {
        const float* qp = q + ((size_t)b * NUM_HEADS + h * GROUP + hg) * HEAD_DIM;
        const float4 a = *(const float4*)(qp + sub * 4);
        const float4 c = *(const float4*)(qp + 64 + sub * 4);
        qv[hg][0] = a.x * qscale; qv[hg][1] = a.y * qscale;
        qv[hg][2] = a.z * qscale; qv[hg][3] = a.w * qscale;
        qv[hg][4] = c.x * qscale; qv[hg][5] = c.y * qscale;
        qv[hg][6] = c.z * qscale; qv[hg][7] = c.w * qscale;
    }

    float m[GROUP], ssum[GROUP], o[GROUP][8];
#pragma unroll
    for (int hg = 0; hg < GROUP; ++hg) {
        m[hg] = -INFINITY; ssum[hg] = 0.f;
#pragma unroll
        for (int j = 0; j < 8; ++j) o[hg][j] = 0.f;
    }

    const int lbase = chunk * CHUNK;
    const float* knew_row = knew + ((size_t)b * NUM_KV_HEADS + h) * HEAD_DIM;
    const float* vnew_row = vnew + ((size_t)b * NUM_KV_HEADS + h) * HEAD_DIM;

    for (int it = 0; it < CHUNK / 16; ++it) {
        const int l   = lbase + it * 16 + wid * 4 + g;
        const int idx = page_indices[b * KV_LEN + l];

        const float* kr;
        const float* vr;
        if (l == KV_LEN - 1) {          // the freshly written token (permutation => only hit)
            kr = knew_row; vr = vnew_row;
        } else {
            kr = k_cache + ((size_t)idx * NUM_KV_HEADS + h) * HEAD_DIM;
            vr = v_cache + ((size_t)idx * NUM_KV_HEADS + h) * HEAD_DIM;
        }
        const float4 k0 = *(const float4*)(kr + sub * 4);
        const float4 k1 = *(const float4*)(kr + 64 + sub * 4);
        const float4 v0 = *(const float4*)(vr + sub * 4);
        const float4 v1 = *(const float4*)(vr + 64 + sub * 4);

        float sc[GROUP];
#pragma unroll
        for (int hg = 0; hg < GROUP; ++hg) {
            sc[hg] = qv[hg][0] * k0.x + qv[hg][1] * k0.y + qv[hg][2] * k0.z + qv[hg][3] * k0.w
                   + qv[hg][4] * k1.x + qv[hg][5] * k1.y + qv[hg][6] * k1.z + qv[hg][7] * k1.w;
        }
#pragma unroll
        for (int off = 1; off < 16; off <<= 1) {
#pragma unroll
            for (int hg = 0; hg < GROUP; ++hg)
                sc[hg] += __shfl_xor(sc[hg], off, 64);
        }
#pragma unroll
        for (int hg = 0; hg < GROUP; ++hg) {
            const float mn = fmaxf(m[hg], sc[hg]);
            const float cf = exp2f(m[hg] - mn);
            const float pr = exp2f(sc[hg] - mn);
            ssum[hg] = ssum[hg] * cf + pr;
            m[hg] = mn;
            o[hg][0] = o[hg][0] * cf + pr * v0.x;
            o[hg][1] = o[hg][1] * cf + pr * v0.y;
            o[hg][2] = o[hg][2] * cf + pr * v0.z;
            o[hg][3] = o[hg][3] * cf + pr * v0.w;
            o[hg][4] = o[hg][4] * cf + pr * v1.x;
            o[hg][5] = o[hg][5] * cf + pr * v1.y;
            o[hg][6] = o[hg][6] * cf + pr * v1.z;
            o[hg][7] = o[hg][7] * cf + pr * v1.w;
        }
    }

    // combine the 4 position-groups within the wave (partner lanes share `sub`)
#pragma unroll
    for (int off = 16; off <= 32; off <<= 1) {
#pragma unroll
        for (int hg = 0; hg < GROUP; ++hg) {
            const float mo = __shfl_xor(m[hg], off, 64);
            const float so = __shfl_xor(ssum[hg], off, 64);
            float oo[8];
#pragma unroll
            for (int j = 0; j < 8; ++j) oo[j] = __shfl_xor(o[hg][j], off, 64);
            const float mn = fmaxf(m[hg], mo);
            const float c1 = exp2f(m[hg] - mn);
            const float c2 = exp2f(mo - mn);
            ssum[hg] = ssum[hg] * c1 + so * c2;
#pragma unroll
            for (int j = 0; j < 8; ++j) o[hg][j] = o[hg][j] * c1 + oo[j] * c2;
            m[hg] = mn;
        }
    }

    // combine the 4 waves via LDS
    __shared__ float red_o[4][GROUP][HEAD_DIM];
    __shared__ float red_m[4][GROUP];
    __shared__ float red_s[4][GROUP];
    if (lane < 16) {
#pragma unroll
        for (int hg = 0; hg < GROUP; ++hg) {
            *(float4*)&red_o[wid][hg][sub * 4]      = make_float4(o[hg][0], o[hg][1], o[hg][2], o[hg][3]);
            *(float4*)&red_o[wid][hg][64 + sub * 4] = make_float4(o[hg][4], o[hg][5], o[hg][6], o[hg][7]);
        }
        if (sub == 0) {
#pragma unroll
            for (int hg = 0; hg < GROUP; ++hg) { red_m[wid][hg] = m[hg]; red_s[wid][hg] = ssum[hg]; }
        }
    }
    __syncthreads();

    if (wid == 0) {  // wave 0: lane = hg*16 + sub finalizes head hg, dims of sub
        const int hg = g;
        const float mn = fmaxf(fmaxf(red_m[0][hg], red_m[1][hg]),
                               fmaxf(red_m[2][hg], red_m[3][hg]));
        float stot = 0.f;
        float acc[8] = {0.f,0.f,0.f,0.f,0.f,0.f,0.f,0.f};
#pragma unroll
        for (int w = 0; w < 4; ++w) {
            const float c = exp2f(red_m[w][hg] - mn);
            stot += red_s[w][hg] * c;
#pragma unroll
            for (int j = 0; j < 4; ++j) acc[j]     += red_o[w][hg][sub * 4 + j] * c;
#pragma unroll
            for (int j = 0; j < 4; ++j) acc[4 + j] += red_o[w][hg][64 + sub * 4 + j] * c;
        }
        const size_t pbase = (((size_t)chunk * BS + b) * NUM_KV_HEADS + h) * GROUP + hg;
        float* op = ws_o + pbase * HEAD_DIM;
        *(float4*)(op + sub * 4)      = make_float4(acc[0], acc[1], acc[2], acc[3]);
        *(float4*)(op + 64 + sub * 4) = make_float4(acc[4], acc[5], acc[6], acc[7]);
        if (sub == 0) { ws_m[pbase] = mn; ws_s[pbase] = stot; }
    }
}

// Combine NCHUNK partials per (b, kv_head, group_head); one block per output head row.
__global__ __launch_bounds__(128) void attn_combine_kernel(
    const float* __restrict__ ws_o,
    const float* __restrict__ ws_m,
    const float* __restrict__ ws_s,
    float* __restrict__ out)
{
    const int bid = blockIdx.x;               // BS * NUM_KV_HEADS * GROUP = 512
    const int hg  = bid % GROUP;
    const int h   = (bid / GROUP) % NUM_KV_HEADS;
    const int b   = bid / (GROUP * NUM_KV_HEADS);
    const int d   = threadIdx.x;

    float mv[NCHUNK];
    float mx = -INFINITY;
#pragma unroll
    for (int c = 0; c < NCHUNK; ++c) {
        mv[c] = ws_m[(((size_t)c * BS + b) * NUM_KV_HEADS + h) * GROUP + hg];
        mx = fmaxf(mx, mv[c]);
    }
    float stot = 0.f, acc = 0.f;
#pragma unroll
    for (int c = 0; c < NCHUNK; ++c) {
        const size_t pbase = (((size_t)c * BS + b) * NUM_KV_HEADS + h) * GROUP + hg;
        const float cf = exp2f(mv[c] - mx);
        stot += ws_s[pbase] * cf;
        acc  += ws_o[pbase * HEAD_DIM + d] * cf;
    }
    out[((size_t)b * NUM_HEADS + h * GROUP + hg) * HEAD_DIM + d] = acc / stot;
}

extern "C" void kernel_launch(void* const* d_in, const int* in_sizes, int n_in,
                              void* d_out, int out_size, void* d_ws, size_t ws_size,
                              hipStream_t stream)
{
    const float* q       = (const float*)d_in[0];
    const float* k       = (const float*)d_in[1];
    const float* v       = (const float*)d_in[2];
    const float* k_cache = (const float*)d_in[3];
    const float* v_cache = (const float*)d_in[4];
    // d_in[5] = slot_mapping (== page_indices[:, -1], handled via l == KV_LEN-1 rule)
    const int* page_indices = (const int*)d_in[6];
    float* out = (float*)d_out;

    float* ws_o = (float*)d_ws;                                               // 2 MB
    float* ws_m = ws_o + (size_t)NCHUNK * BS * NUM_KV_HEADS * GROUP * HEAD_DIM;
    float* ws_s = ws_m + (size_t)NCHUNK * BS * NUM_KV_HEADS * GROUP;

    attn_partial_kernel<<<BS * NUM_KV_HEADS * NCHUNK, 256, 0, stream>>>(
        q, k, v, k_cache, v_cache, page_indices, ws_o, ws_m, ws_s);
    attn_combine_kernel<<<BS * NUM_KV_HEADS * GROUP, 128, 0, stream>>>(
        ws_o, ws_m, ws_s, out);
}